// Round 18
// baseline (51.900 us; speedup 1.0000x reference)
//
#include <hip/hip_runtime.h>

#define KK 5
#define RR 2
#define N_ 2
#define C_ 256
#define H_ 128
#define W_ 128
#define H2 256
#define W2 256
#define TW 32              // tile width in source pixels
#define TH 8               // tile height
#define CCHUNK 8
#define PHh 12             // TH + 4 halo rows
#define PWw 36             // TW + 4 real halo cols
#define PWST 37            // LDS row stride in px: 148 words, mod-32 = 20 -> all 8 bank-groups
#define NPIX (PHh*PWw)     // 432 real halo pixels
#define PLANE (PHh*PWST*4) // 1776 words per 4-channel plane
#define HW (H_*W_)
#define HW2 (H2*W2)
#define DEPTH 4            // mask prefetch ring depth

typedef float f32x4 __attribute__((ext_vector_type(4)));   // native vec for nontemporal builtin

__global__ __launch_bounds__(256) void carafe_kernel(
    const float* __restrict__ feat,
    const float* __restrict__ masks,
    float* __restrict__ out)
{
    // Channel-group-planar, row stride 37 px: word = G*PLANE + (py*37+px)*4 + t.
    // Thread = (pixel pair 2u,2u+1) x (4-ch plane G): per dy the 6-px union row
    // is read once (6 b128) and reused across 5 dx -> 30 reads vs 50, same FMA.
    __shared__ float patch[2 * PLANE];   // 3552 words = 14208 B

    const int tid = threadIdx.x;
    const int G   = tid >> 7;          // channel-quad plane (wave-uniform)
    const int pp  = tid & 127;
    const int u   = pp & 15;           // pixel-pair index: owns px 2u, 2u+1
    const int ty  = pp >> 4;           // 0..7

    // XCD-bijective swizzle, chunk-fastest (R12: FETCH 68->28.6 MB).
    const int bid   = blockIdx.x;
    const int xcd   = bid & 7;
    const int s     = bid >> 3;
    const int chunk = s & 31;
    const int tn    = xcd * 16 + (s >> 5);   // tile-n index 0..127
    const int tile  = tn & 63;
    const int n     = tn >> 6;
    const int bx    = tile & 3;              // W_/TW = 4
    const int by    = tile >> 2;             // H_/TH = 16
    const int c0    = chunk * CCHUNK;

    const int i0 = by * TH + ty;
    const int j0 = bx * TW + 2 * u;          // first source col of the pair
    const int gy0 = by * TH - RR;
    const int gx0 = bx * TW - RR;

    // ---- stage 8 channels' 12x36 halo: 864 b128 slots, 4 rounds ----
    const float* fbase = feat + (size_t)(n * C_ + c0) * HW;
    #pragma unroll
    for (int r = 0; r < 4; ++r) {
        const int idx = tid + r * 256;
        if (idx < 2 * NPIX) {
            const int Gs = idx >= NPIX;
            const int p  = idx - Gs * NPIX;
            const int py = p / PWw;
            const int px = p - py * PWw;
            const int gy = gy0 + py;
            const int gx = gx0 + px;
            float4 v = make_float4(0.f, 0.f, 0.f, 0.f);
            if ((unsigned)gy < (unsigned)H_ && (unsigned)gx < (unsigned)W_) {
                const float* fp = fbase + (4 * Gs) * HW + gy * W_ + gx;
                v.x = fp[0];
                v.y = fp[HW];
                v.z = fp[2 * HW];
                v.w = fp[3 * HW];
            }
            *reinterpret_cast<float4*>(&patch[Gs * PLANE + (py * PWST + px) * 4]) = v;
        }
    }

    // ---- mask ring preload: float4 per row (4 output cols), 2 rows ----
    const float* mb = masks + ((size_t)n * (KK * KK) * H2 + (size_t)(2 * i0)) * W2 + 2 * j0;
    float4 q0[DEPTH], q1[DEPTH];
    #pragma unroll
    for (int t = 0; t < DEPTH; ++t) {
        q0[t] = *reinterpret_cast<const float4*>(mb + (size_t)t * HW2);
        q1[t] = *reinterpret_cast<const float4*>(mb + (size_t)t * HW2 + W2);
    }
    __syncthreads();

    // ---- dy-outer: read 6-px union row once, reuse across 5 dx ----
    float acc[4][2][4] = {};   // [t ch][a row][b col]; cols 0-1 from px0, 2-3 from px1
    const int rbase = G * PLANE;

    #pragma unroll
    for (int dy = 0; dy < KK; ++dy) {
        const int row = ty + dy;
        float4 w[6];
        #pragma unroll
        for (int j = 0; j < 6; ++j)
            w[j] = *reinterpret_cast<const float4*>(&patch[rbase + (row * PWST + 2 * u + j) * 4]);

        #pragma unroll
        for (int dx = 0; dx < KK; ++dx) {
            const int k = dy * KK + dx;
            const float4 m0 = q0[k % DEPTH];   // static index after unroll
            const float4 m1 = q1[k % DEPTH];
            if (k + DEPTH < KK * KK) {
                q0[k % DEPTH] = *reinterpret_cast<const float4*>(mb + (size_t)(k + DEPTH) * HW2);
                q1[k % DEPTH] = *reinterpret_cast<const float4*>(mb + (size_t)(k + DEPTH) * HW2 + W2);
            }
            const float w0[4] = { w[dx].x,     w[dx].y,     w[dx].z,     w[dx].w     };
            const float w1[4] = { w[dx + 1].x, w[dx + 1].y, w[dx + 1].z, w[dx + 1].w };
            #pragma unroll
            for (int t = 0; t < 4; ++t) {
                acc[t][0][0] += w0[t] * m0.x;  acc[t][0][1] += w0[t] * m0.y;
                acc[t][0][2] += w1[t] * m0.z;  acc[t][0][3] += w1[t] * m0.w;
                acc[t][1][0] += w0[t] * m1.x;  acc[t][1][1] += w0[t] * m1.y;
                acc[t][1][2] += w1[t] * m1.z;  acc[t][1][3] += w1[t] * m1.w;
            }
        }
    }

    // ---- store: 4 ch x 2 rows, one NT dwordx4 (4 output cols) each ----
    float* ob = out + ((size_t)(n * C_ + c0 + 4 * G) * H2 + (size_t)(2 * i0)) * W2 + 2 * j0;
    #pragma unroll
    for (int t = 0; t < 4; ++t) {
        f32x4 r0; r0.x = acc[t][0][0]; r0.y = acc[t][0][1]; r0.z = acc[t][0][2]; r0.w = acc[t][0][3];
        f32x4 r1; r1.x = acc[t][1][0]; r1.y = acc[t][1][1]; r1.z = acc[t][1][2]; r1.w = acc[t][1][3];
        __builtin_nontemporal_store(r0, reinterpret_cast<f32x4*>(ob));
        __builtin_nontemporal_store(r1, reinterpret_cast<f32x4*>(ob + W2));
        ob += (size_t)HW2;
    }
}

extern "C" void kernel_launch(void* const* d_in, const int* in_sizes, int n_in,
                              void* d_out, int out_size, void* d_ws, size_t ws_size,
                              hipStream_t stream) {
    const float* feat  = (const float*)d_in[0];
    const float* masks = (const float*)d_in[1];
    float* out = (float*)d_out;

    // 4096 blocks flat: 64 tiles x 32 chunks x 2 batch, XCD-swizzled in-kernel
    carafe_kernel<<<dim3(4096), dim3(256), 0, stream>>>(feat, masks, out);
}

// Round 19
// 48.282 us; speedup vs baseline: 1.0749x; 1.0749x over previous
//
#include <hip/hip_runtime.h>

#define KK 5
#define RR 2
#define N_ 2
#define C_ 256
#define H_ 128
#define W_ 128
#define H2 256
#define W2 256
#define TW 32              // tile width in source pixels (wide -> 256B write runs)
#define TH 8               // tile height
#define CCHUNK 8
#define PHh 12             // TH + 4
#define PWw 36             // TW + 4
#define NPIX (PHh*PWw)     // 432 halo pixels
#define PLANE (NPIX*4)     // words per 4-channel plane
#define HW (H_*W_)
#define HW2 (H2*W2)
#define DEPTH 4            // mask prefetch ring depth

typedef float f32x2 __attribute__((ext_vector_type(2)));   // native vec for nontemporal builtin

__global__ __launch_bounds__(256) void carafe_kernel(
    const float* __restrict__ feat,
    const float* __restrict__ masks,
    float* __restrict__ out)
{
    // Channel-group-planar: word = G*PLANE + p*4 + t holds channel c0+4G+t at
    // halo pixel p. Lane-adjacent b128 ops stride 4 words -> uniform 8
    // words/bank = conflict floor (measured 0 conflicts since R12).
    __shared__ float patch[2 * PLANE];   // 3456 words = 13824 B

    const int tid = threadIdx.x;
    const int tx = tid & 31;           // source col within tile
    const int ty = tid >> 5;           // source row within tile (0..7)

    // XCD-bijective swizzle: all 32 chunks of a tile run consecutively on the
    // SAME XCD -> tile's masks enter exactly one L2 (R12: FETCH 68->28.6 MB).
    const int bid   = blockIdx.x;
    const int xcd   = bid & 7;
    const int s     = bid >> 3;
    const int chunk = s & 31;
    const int tn    = xcd * 16 + (s >> 5);   // tile-n index 0..127
    const int tile  = tn & 63;
    const int n     = tn >> 6;
    const int bx    = tile & 3;              // W_/TW = 4
    const int by    = tile >> 2;             // H_/TH = 16
    const int c0    = chunk * CCHUNK;

    const int i0 = by * TH + ty;
    const int j0 = bx * TW + tx;
    const int gy0 = by * TH - RR;
    const int gx0 = bx * TW - RR;

    // ---- stage 8 channels' 12x36 halo: 864 b128 slots, 4 rounds ----
    const float* fbase = feat + (size_t)(n * C_ + c0) * HW;
    #pragma unroll
    for (int r = 0; r < 4; ++r) {
        const int idx = tid + r * 256;
        if (idx < 2 * NPIX) {
            const int G  = idx >= NPIX;
            const int p  = idx - G * NPIX;
            const int py = p / PWw;
            const int px = p - py * PWw;
            const int gy = gy0 + py;
            const int gx = gx0 + px;
            float4 v = make_float4(0.f, 0.f, 0.f, 0.f);
            if ((unsigned)gy < (unsigned)H_ && (unsigned)gx < (unsigned)W_) {
                const float* fp = fbase + (4 * G) * HW + gy * W_ + gx;
                v.x = fp[0];
                v.y = fp[HW];
                v.z = fp[2 * HW];
                v.w = fp[3 * HW];
            }
            *reinterpret_cast<float4*>(&patch[G * PLANE + p * 4]) = v;
        }
    }

    // ---- mask ring preload (latency hides under staging drain + barrier) ----
    const float* mb = masks + ((size_t)n * (KK * KK) * H2 + (size_t)(2 * i0)) * W2 + 2 * j0;
    float2 q0[DEPTH], q1[DEPTH];
    #pragma unroll
    for (int t = 0; t < DEPTH; ++t) {
        q0[t] = *reinterpret_cast<const float2*>(mb + (size_t)t * HW2);
        q1[t] = *reinterpret_cast<const float2*>(mb + (size_t)t * HW2 + W2);
    }
    __syncthreads();

    // ---- k-outer with explicit one-iter LDS read pipeline ----
    float acc[CCHUNK][2][2] = {};
    const int p0 = ty * PWw + tx;

    // prime: read k=0's values
    float4 v0c = *reinterpret_cast<const float4*>(&patch[p0 * 4]);
    float4 v1c = *reinterpret_cast<const float4*>(&patch[PLANE + p0 * 4]);

    #pragma unroll
    for (int k = 0; k < KK * KK; ++k) {
        const float2 m0 = q0[k % DEPTH];   // static index after unroll
        const float2 m1 = q1[k % DEPTH];
        if (k + DEPTH < KK * KK) {
            q0[k % DEPTH] = *reinterpret_cast<const float2*>(mb + (size_t)(k + DEPTH) * HW2);
            q1[k % DEPTH] = *reinterpret_cast<const float2*>(mb + (size_t)(k + DEPTH) * HW2 + W2);
        }

        // issue next iteration's LDS reads BEFORE this iteration's FMAs
        float4 v0n, v1n;
        if (k + 1 < KK * KK) {
            const int k1  = k + 1;
            const int P1  = p0 + (k1 / KK) * PWw + (k1 % KK);   // compile-time delta
            v0n = *reinterpret_cast<const float4*>(&patch[P1 * 4]);
            v1n = *reinterpret_cast<const float4*>(&patch[PLANE + P1 * 4]);
        }

        acc[0][0][0] += v0c.x * m0.x;  acc[0][0][1] += v0c.x * m0.y;
        acc[0][1][0] += v0c.x * m1.x;  acc[0][1][1] += v0c.x * m1.y;
        acc[1][0][0] += v0c.y * m0.x;  acc[1][0][1] += v0c.y * m0.y;
        acc[1][1][0] += v0c.y * m1.x;  acc[1][1][1] += v0c.y * m1.y;
        acc[2][0][0] += v0c.z * m0.x;  acc[2][0][1] += v0c.z * m0.y;
        acc[2][1][0] += v0c.z * m1.x;  acc[2][1][1] += v0c.z * m1.y;
        acc[3][0][0] += v0c.w * m0.x;  acc[3][0][1] += v0c.w * m0.y;
        acc[3][1][0] += v0c.w * m1.x;  acc[3][1][1] += v0c.w * m1.y;
        acc[4][0][0] += v1c.x * m0.x;  acc[4][0][1] += v1c.x * m0.y;
        acc[4][1][0] += v1c.x * m1.x;  acc[4][1][1] += v1c.x * m1.y;
        acc[5][0][0] += v1c.y * m0.x;  acc[5][0][1] += v1c.y * m0.y;
        acc[5][1][0] += v1c.y * m1.x;  acc[5][1][1] += v1c.y * m1.y;
        acc[6][0][0] += v1c.z * m0.x;  acc[6][0][1] += v1c.z * m0.y;
        acc[6][1][0] += v1c.z * m1.x;  acc[6][1][1] += v1c.z * m1.y;
        acc[7][0][0] += v1c.w * m0.x;  acc[7][0][1] += v1c.w * m0.y;
        acc[7][1][0] += v1c.w * m1.x;  acc[7][1][1] += v1c.w * m1.y;

        if (k + 1 < KK * KK) { v0c = v0n; v1c = v1n; }   // register rename
    }

    // ---- store: nontemporal float2 rows (write stream never re-read) ----
    float* ob = out + ((size_t)(n * C_ + c0) * H2 + (size_t)(2 * i0)) * W2 + 2 * j0;
    #pragma unroll
    for (int c = 0; c < CCHUNK; ++c) {
        f32x2 r0; r0.x = acc[c][0][0]; r0.y = acc[c][0][1];
        f32x2 r1; r1.x = acc[c][1][0]; r1.y = acc[c][1][1];
        __builtin_nontemporal_store(r0, reinterpret_cast<f32x2*>(ob));
        __builtin_nontemporal_store(r1, reinterpret_cast<f32x2*>(ob + W2));
        ob += (size_t)HW2;
    }
}

extern "C" void kernel_launch(void* const* d_in, const int* in_sizes, int n_in,
                              void* d_out, int out_size, void* d_ws, size_t ws_size,
                              hipStream_t stream) {
    const float* feat  = (const float*)d_in[0];
    const float* masks = (const float*)d_in[1];
    float* out = (float*)d_out;

    // 4096 blocks flat: 64 tiles x 32 chunks x 2 batch, XCD-swizzled in-kernel
    carafe_kernel<<<dim3(4096), dim3(256), 0, stream>>>(feat, masks, out);
}